// Round 9
// baseline (310.793 us; speedup 1.0000x reference)
//
#include <hip/hip_runtime.h>
#include <hip/hip_bf16.h>

// MultiheadAttention with relative position bias, MI355X gfx950.
// L=1024, B=16, E=512, H=8, d=64. Inputs/output fp32; ws intermediates fp16.
//
// Stage 1: qkv_kernel   -- MFMA in_proj GEMMs -> Q,K fp16 (B,H,L,64) and V directly
//                          TRANSPOSED to Vt (B,H,64,L) via LDS-transpose epilogue
//                          (R16: transpose_v kernel deleted; q pre-scaled 1/8*log2e)
// Stage 2: attn_kernel  -- MFMA flash attention w/ RPE bias -> CTX fp16 (L,B,E)
//                          R16: double-buffered K/V LDS, ONE barrier per j-iter
//                          (R10 qkv pattern); in-loop idx loads; hardware exp2
// Stage 3: out_kernel   -- MFMA out_proj GEMM -> fp32 output (L,B,E), R10 pipeline
//
// ws (fp16 elems): Q @0, K @8M, Vt @16M, CTX @24M.
//
// MFMA f16 16x16x32 layouts (verified end-to-end in this problem, round 4):
//   A[m=lane&15][k=quad*8+j], B[k=quad*8+j][n=lane&15], D[row=quad*4+reg][col=lane&15]

#define L_SEQ 1024
#define B_N   16
#define E_DIM 512
#define H_N   8
#define NREL  2047
#define LOG2E 1.44269504f

typedef _Float16 f16;
using half4   = __attribute__((ext_vector_type(4))) _Float16;
using half8   = __attribute__((ext_vector_type(8))) _Float16;
using floatx4 = __attribute__((ext_vector_type(4))) float;

// lgkmcnt(0) drain (ds_write visibility) + raw barrier, pinned against code motion.
// Does NOT drain vmcnt -> global loads stay in flight across the barrier.
#define LGKM_BARRIER() do {                                   \
    asm volatile("s_waitcnt lgkmcnt(0)" ::: "memory");        \
    __builtin_amdgcn_sched_barrier(0);                        \
    __builtin_amdgcn_s_barrier();                             \
    __builtin_amdgcn_sched_barrier(0);                        \
} while (0)

// raw hardware exp2 (single v_exp_f32; ~1ulp, no denormal fixup -- inputs O(10)).
__device__ __forceinline__ float fast_exp2(float x) {
    return __builtin_amdgcn_exp2f(x);
}

__device__ __forceinline__ half4 cvt4(const float4 a) {
    half4 h;
    h[0] = (f16)a.x; h[1] = (f16)a.y; h[2] = (f16)a.z; h[3] = (f16)a.w;
    return h;
}

// ---------------------------------------------------------------------------
// Stage 1: in_proj MFMA GEMM. 1536 blocks, XCD-swizzled. R10 pipeline.
// proj==2 epilogue: LDS-transpose (reuses staging LDS) -> direct Vt stores,
// 16B (8 l) per store, fully replacing the old transpose_v kernel.
// ---------------------------------------------------------------------------
__global__ __launch_bounds__(256) void qkv_kernel(
    const float* __restrict__ Xq, const float* __restrict__ Xk, const float* __restrict__ Xv,
    const float* __restrict__ W, const float* __restrict__ Bias,
    f16* __restrict__ Qo, f16* __restrict__ Ko, f16* __restrict__ Vt)
{
    // swizzle: xcd = flat&7; 48 groups (m,proj) per XCD; 4 f-tiles per group
    const int flat = blockIdx.x;
    const int xcd  = flat & 7;
    const int slot = flat >> 3;            // 0..191
    const int g    = xcd * 48 + (slot >> 2);   // 0..383 = proj*128 + mtile
    const int f0   = (slot & 3) << 7;
    const int proj = g >> 7;               // 0=q 1=k 2=v
    const int n0   = (g & 127) << 7;

    const float* X  = (proj == 0) ? Xq : (proj == 1) ? Xk : Xv;
    const float* Wp = W + (size_t)(proj << 9) * E_DIM;

    // 40KB shared, aliased: loop uses As/Bs (f16 [2][128][40] each);
    // proj==2 epilogue reuses it as T[128][138] (odd word-stride: bank spread).
    __shared__ __align__(16) char smem[40960];
    auto As = reinterpret_cast<f16(*)[128][40]>(smem);
    auto Bs = reinterpret_cast<f16(*)[128][40]>(smem + 20480);
    auto T  = reinterpret_cast<f16(*)[138]>(smem);

    const int tid  = threadIdx.x;
    const int w    = tid >> 6;
    const int lane = tid & 63;
    const int quad = lane >> 4, c = lane & 15;
    const int wm = (w >> 1) << 6, wn = (w & 1) << 6;

    // staging: wave w covers rows [w*32, w*32+32); instr i: row = w*32+i*8+(lane>>3),
    // cols (lane&7)*4 .. +3 (fp32) -> 8 rows x 128 B contiguous segments per instr.
    const int srow = (w << 5) + (lane >> 3);     // + i*8
    const int scol = (lane & 7) << 2;
    const float* Xg = X  + (size_t)(n0 + srow) * E_DIM + scol;
    const float* Wg = Wp + (size_t)(f0 + srow) * E_DIM + scol;

    float4 lx[4], lw[4];
    auto load_tile = [&](int kk) {
#pragma unroll
        for (int i = 0; i < 4; ++i)
            lx[i] = *reinterpret_cast<const float4*>(Xg + (size_t)(i * 8) * E_DIM + kk);
#pragma unroll
        for (int i = 0; i < 4; ++i)
            lw[i] = *reinterpret_cast<const float4*>(Wg + (size_t)(i * 8) * E_DIM + kk);
    };
    auto write_tile = [&](int buf) {
#pragma unroll
        for (int i = 0; i < 4; ++i)
            *reinterpret_cast<half4*>(&As[buf][srow + i * 8][scol]) = cvt4(lx[i]);
#pragma unroll
        for (int i = 0; i < 4; ++i)
            *reinterpret_cast<half4*>(&Bs[buf][srow + i * 8][scol]) = cvt4(lw[i]);
    };

    floatx4 acc[4][4] = {};

    // prologue: tile0 staged+visible; tile1 loads in flight
    load_tile(0);
    write_tile(0);
    load_tile(32);
    LGKM_BARRIER();

    for (int t = 0; t < 16; ++t) {
        const int cur = t & 1;

        half8 a[4], bfr[4];
#pragma unroll
        for (int mt = 0; mt < 4; ++mt)
            a[mt] = *reinterpret_cast<const half8*>(&As[cur][wm + mt * 16 + c][quad * 8]);
#pragma unroll
        for (int nt = 0; nt < 4; ++nt)
            bfr[nt] = *reinterpret_cast<const half8*>(&Bs[cur][wn + nt * 16 + c][quad * 8]);
#pragma unroll
        for (int mt = 0; mt < 4; ++mt)
#pragma unroll
            for (int nt = 0; nt < 4; ++nt)
                acc[mt][nt] = __builtin_amdgcn_mfma_f32_16x16x32_f16(a[mt], bfr[nt], acc[mt][nt], 0, 0, 0);

        if (t < 15) {
            write_tile(cur ^ 1);               // cvt consumes loads(t+1); auto vmcnt wait
            if (t < 14) load_tile((t + 2) * 32);  // regs free -> issue next, flies over barrier
        }
        LGKM_BARRIER();
    }

    if (proj != 2) {
        f16* Dst = (proj == 0) ? Qo : Ko;
        // q pre-scale folds softmax base-change: exp(x) = exp2(x*log2e)
        const float scale = (proj == 0) ? (0.125f * LOG2E) : 1.0f;
#pragma unroll
        for (int nt = 0; nt < 4; ++nt) {
            const int fl = f0 + wn + nt * 16 + c;
            const float bj = Bias[(proj << 9) + fl];
            const int h = fl >> 6, d = fl & 63;
#pragma unroll
            for (int mt = 0; mt < 4; ++mt) {
#pragma unroll
                for (int r = 0; r < 4; ++r) {
                    const int n = n0 + wm + mt * 16 + quad * 4 + r;
                    const int l = n >> 4, b = n & 15;
                    Dst[((((size_t)b * H_N + h) * L_SEQ + l) << 6) + d] =
                        (f16)((acc[mt][nt][r] + bj) * scale);
                }
            }
        }
    } else {
        // V: write acc (+bias) transposed into T[f_local][n_local]; after the
        // final loop barrier all LDS reads of As/Bs are done -> safe to alias.
#pragma unroll
        for (int nt = 0; nt < 4; ++nt) {
            const int fl = wn + nt * 16 + c;
            const float bj = Bias[(2 << 9) + f0 + fl];
#pragma unroll
            for (int mt = 0; mt < 4; ++mt)
#pragma unroll
                for (int r = 0; r < 4; ++r)
                    T[fl][wm + mt * 16 + quad * 4 + r] = (f16)(acc[mt][nt][r] + bj);
        }
        __syncthreads();

        // store: thread handles (b, h-half, d); 8 l values = 16B contiguous in Vt
        const int l0 = n0 >> 4;
        const int hbase = f0 >> 6;
#pragma unroll
        for (int i = 0; i < 8; ++i) {
            const int idx2 = i * 256 + tid;      // 0..2047
            const int d  = idx2 & 63;
            const int hh = (idx2 >> 6) & 1;
            const int bb = idx2 >> 7;            // 0..15
            const int fl = hh * 64 + d;
            union { f16 h[8]; uint4 u; } pk;
#pragma unroll
            for (int j = 0; j < 8; ++j) pk.h[j] = T[fl][j * 16 + bb];
            f16* dst = Vt + (((size_t)(bb * H_N + hbase + hh)) << 16) + (size_t)d * 1024 + l0;
            *reinterpret_cast<uint4*>(dst) = pk.u;
        }
    }
}

// ---------------------------------------------------------------------------
// Stage 2: MFMA flash attention, fixed-max softmax. 1024 blocks, block 256.
// R16: double-buffered Ks/Vts, ONE lgkm-barrier per j-iter (write next tile
// from prefetch regs before compute; readers of that buffer finished at the
// previous barrier). In-loop idx loads; hardware exp2 (tab pre-scaled log2e).
// XCD swizzle: the 8 q-tile blocks of each (b,h) share K/V through one L2.
// ---------------------------------------------------------------------------
__global__ __launch_bounds__(256, 2) void attn_kernel(
    const f16* __restrict__ Q, const f16* __restrict__ K, const f16* __restrict__ Vt,
    const int* __restrict__ RPE, const float* __restrict__ Tab, f16* __restrict__ CTX)
{
    // swizzle: xcd = flat&7; bh = (slot>>3)*8 + xcd; q-tile = slot&7
    const int flat = blockIdx.x;
    const int xcd  = flat & 7;
    const int slot = flat >> 3;            // 0..127
    const int q0   = (slot & 7) << 7;
    const int bh   = ((slot >> 3) << 3) + xcd;
    const int b = bh >> 3, h = bh & 7;

    const int tid  = threadIdx.x;
    const int w    = tid >> 6;
    const int lane = tid & 63;
    const int quad = lane >> 4, c = lane & 15;

    __shared__ __align__(16) f16 Ks[2][64][72];
    __shared__ __align__(16) f16 Vts[2][64][72];
    __shared__ __align__(16) f16 Pw[4][32][72];
    __shared__ float tab[NREL];

    const size_t base = (size_t)bh << 16;

    // tab pre-scaled by log2e: exp(s+t) == exp2(s*log2e + t*log2e)
    for (int i = tid; i < NREL; i += 256) tab[i] = Tab[h * NREL + i] * LOG2E;

    const int qg0 = q0 + (w << 5);
    half8 Aq[2][2];
#pragma unroll
    for (int s = 0; s < 2; ++s) {
        const f16* qp = Q + base + (size_t)(qg0 + s * 16 + c) * 64 + quad * 8;
        Aq[s][0] = *reinterpret_cast<const half8*>(qp);
        Aq[s][1] = *reinterpret_cast<const half8*>(qp + 32);
    }

    floatx4 o[2][4] = {};
    float l_part[2][4] = {};

    const int* rp = RPE + (size_t)(qg0 + (quad << 2)) * 1024 + c;

    const int sr = tid >> 2, so = (tid & 3) << 4;
    const f16* kbase = K  + base + (size_t)sr * 64 + so;
    const f16* vbase = Vt + base + (size_t)sr * 1024 + so;

    // prologue: tile0 -> buf0; tile1 -> regs; barrier covers tab + buf0
    uint4 pk0 = *reinterpret_cast<const uint4*>(kbase);
    uint4 pk1 = *reinterpret_cast<const uint4*>(kbase + 8);
    uint4 pv0 = *reinterpret_cast<const uint4*>(vbase);
    uint4 pv1 = *reinterpret_cast<const uint4*>(vbase + 8);
    *reinterpret_cast<uint4*>(&Ks[0][sr][so])      = pk0;
    *reinterpret_cast<uint4*>(&Ks[0][sr][so + 8])  = pk1;
    *reinterpret_cast<uint4*>(&Vts[0][sr][so])     = pv0;
    *reinterpret_cast<uint4*>(&Vts[0][sr][so + 8]) = pv1;
    pk0 = *reinterpret_cast<const uint4*>(kbase + 64 * 64);
    pk1 = *reinterpret_cast<const uint4*>(kbase + 64 * 64 + 8);
    pv0 = *reinterpret_cast<const uint4*>(vbase + 64);
    pv1 = *reinterpret_cast<const uint4*>(vbase + 64 + 8);
    LGKM_BARRIER();

    for (int t = 0; t < 16; ++t) {
        const int cur = t & 1;
        const int j0  = t << 6;

        if (t < 15) {
            // write NEXT tile from regs (its readers finished at the prev barrier)
            *reinterpret_cast<uint4*>(&Ks[cur ^ 1][sr][so])      = pk0;
            *reinterpret_cast<uint4*>(&Ks[cur ^ 1][sr][so + 8])  = pk1;
            *reinterpret_cast<uint4*>(&Vts[cur ^ 1][sr][so])     = pv0;
            *reinterpret_cast<uint4*>(&Vts[cur ^ 1][sr][so + 8]) = pv1;
            if (t < 14) {
                const f16* kn = kbase + (size_t)(t + 2) * 64 * 64;
                const f16* vn = vbase + (t + 2) * 64;
                pk0 = *reinterpret_cast<const uint4*>(kn);
                pk1 = *reinterpret_cast<const uint4*>(kn + 8);
                pv0 = *reinterpret_cast<const uint4*>(vn);
                pv1 = *reinterpret_cast<const uint4*>(vn + 8);
            }
        }

        // idx loads in-loop: their vmcnt wait keeps the conflicted tab gathers
        // out of the QK^T MFMA shadow (R14 lesson).
        int idx[2][4][4];
#pragma unroll
        for (int s = 0; s < 2; ++s)
#pragma unroll
            for (int r = 0; r < 4; ++r)
#pragma unroll
                for (int nt = 0; nt < 4; ++nt)
                    idx[s][r][nt] = rp[(size_t)(s * 16 + r) * 1024 + j0 + nt * 16];

        floatx4 sc[2][4];
#pragma unroll
        for (int nt = 0; nt < 4; ++nt) {
            const half8 b0 = *reinterpret_cast<const half8*>(&Ks[cur][nt * 16 + c][quad * 8]);
            const half8 b1 = *reinterpret_cast<const half8*>(&Ks[cur][nt * 16 + c][32 + quad * 8]);
            floatx4 t0 = {}, t1 = {};
            t0 = __builtin_amdgcn_mfma_f32_16x16x32_f16(Aq[0][0], b0, t0, 0, 0, 0);
            t0 = __builtin_amdgcn_mfma_f32_16x16x32_f16(Aq[0][1], b1, t0, 0, 0, 0);
            t1 = __builtin_amdgcn_mfma_f32_16x16x32_f16(Aq[1][0], b0, t1, 0, 0, 0);
            t1 = __builtin_amdgcn_mfma_f32_16x16x32_f16(Aq[1][1], b1, t1, 0, 0, 0);
            sc[0][nt] = t0; sc[1][nt] = t1;
        }

#pragma unroll
        for (int s = 0; s < 2; ++s)
#pragma unroll
            for (int r = 0; r < 4; ++r) {
                float rs = 0.0f;
#pragma unroll
                for (int nt = 0; nt < 4; ++nt) {
                    const float p = fast_exp2(sc[s][nt][r] + tab[idx[s][r][nt]]);
                    rs += p;
                    Pw[w][s * 16 + quad * 4 + r][nt * 16 + c] = (f16)p;
                }
                l_part[s][r] += rs;
            }

        half8 vb[4][2];
#pragma unroll
        for (int nt = 0; nt < 4; ++nt) {
            vb[nt][0] = *reinterpret_cast<const half8*>(&Vts[cur][nt * 16 + c][quad * 8]);
            vb[nt][1] = *reinterpret_cast<const half8*>(&Vts[cur][nt * 16 + c][32 + quad * 8]);
        }
#pragma unroll
        for (int s = 0; s < 2; ++s) {
            const half8 Ap0 = *reinterpret_cast<const half8*>(&Pw[w][s * 16 + c][quad * 8]);
            const half8 Ap1 = *reinterpret_cast<const half8*>(&Pw[w][s * 16 + c][32 + quad * 8]);
#pragma unroll
            for (int nt = 0; nt < 4; ++nt) {
                o[s][nt] = __builtin_amdgcn_mfma_f32_16x16x32_f16(Ap0, vb[nt][0], o[s][nt], 0, 0, 0);
                o[s][nt] = __builtin_amdgcn_mfma_f32_16x16x32_f16(Ap1, vb[nt][1], o[s][nt], 0, 0, 0);
            }
        }
        LGKM_BARRIER();
    }

#pragma unroll
    for (int s = 0; s < 2; ++s)
#pragma unroll
        for (int r = 0; r < 4; ++r) {
            float l = l_part[s][r];
            l += __shfl_xor(l, 1); l += __shfl_xor(l, 2);
            l += __shfl_xor(l, 4); l += __shfl_xor(l, 8);
            const float inv = 1.0f / l;
            const int lrow = qg0 + s * 16 + quad * 4 + r;
            f16* dp = CTX + ((size_t)(lrow * 16 + b)) * 512 + h * 64;
#pragma unroll
            for (int nt = 0; nt < 4; ++nt)
                dp[nt * 16 + c] = (f16)(o[s][nt][r] * inv);
        }
}

// ---------------------------------------------------------------------------
// Stage 3: out_proj MFMA GEMM. 512 blocks, XCD-swizzled, R10 pipeline.
// A = CTX (f16 pass-through regs); B = W (fp32 -> cvt at write).
// ---------------------------------------------------------------------------
__global__ __launch_bounds__(256) void out_kernel(
    const f16* __restrict__ X, const float* __restrict__ W, const float* __restrict__ Bias,
    float* __restrict__ Out)
{
    // swizzle: 16 m-groups per XCD, 4 f-tiles per group on same XCD
    const int flat = blockIdx.x;
    const int xcd  = flat & 7;
    const int slot = flat >> 3;            // 0..63
    const int m    = xcd * 16 + (slot >> 2);   // 0..127
    const int f0   = (slot & 3) << 7;
    const int n0   = m << 7;

    __shared__ __align__(16) f16 As[2][128][40];
    __shared__ __align__(16) f16 Bs[2][128][40];

    const int tid  = threadIdx.x;
    const int w    = tid >> 6;
    const int lane = tid & 63;
    const int quad = lane >> 4, c = lane & 15;
    const int wm = (w >> 1) << 6, wn = (w & 1) << 6;

    // A staging (f16): instr i: row = w*32 + i*16 + (lane>>2), col = (lane&3)*8
    const int arow = (w << 5) + (lane >> 2);     // + i*16
    const int acol = (lane & 3) << 3;
    const f16* Xg = X + (size_t)(n0 + arow) * E_DIM + acol;

    // B staging (fp32): as qkv
    const int srow = (w << 5) + (lane >> 3);     // + i*8
    const int scol = (lane & 7) << 2;
    const float* Wg = W + (size_t)(f0 + srow) * E_DIM + scol;

    uint4  la[2];
    float4 lw[4];
    auto load_tile = [&](int kk) {
#pragma unroll
        for (int i = 0; i < 2; ++i)
            la[i] = *reinterpret_cast<const uint4*>(Xg + (size_t)(i * 16) * E_DIM + kk);
#pragma unroll
        for (int i = 0; i < 4; ++i)
            lw[i] = *reinterpret_cast<const float4*>(Wg + (size_t)(i * 8) * E_DIM + kk);
    };
    auto write_tile = [&](int buf) {
#pragma unroll
        for (int i = 0; i < 2; ++i)
            *reinterpret_cast<uint4*>(&As[buf][arow + i * 16][acol]) = la[i];
#pragma unroll
        for (int i = 0; i < 4; ++i)
            *reinterpret_cast<half4*>(&Bs[buf][srow + i * 8][scol]) = cvt4(lw[i]);
    };

    floatx4 acc[4][4] = {};

    load_tile(0);
    write_tile(0);
    load_tile(32);
    LGKM_BARRIER();

    for (int t = 0; t < 16; ++t) {
        const int cur = t & 1;

        half8 a[4], bfr[4];
#pragma unroll
        for (int mt = 0; mt < 4; ++mt)
            a[mt] = *reinterpret_cast<const half8*>(&As[cur][wm + mt * 16 + c][quad * 8]);
#pragma unroll
        for (int nt = 0; nt < 4; ++nt)
            bfr[nt] = *reinterpret_cast<const half8*>(&Bs[cur][wn + nt * 16 + c][quad * 8]);
#pragma unroll
        for (int mt = 0; mt < 4; ++mt)
#pragma unroll
            for (int nt = 0; nt < 4; ++nt)
                acc[mt][nt] = __builtin_amdgcn_mfma_f32_16x16x32_f16(a[mt], bfr[nt], acc[mt][nt], 0, 0, 0);

        if (t < 15) {
            write_tile(cur ^ 1);
            if (t < 14) load_tile((t + 2) * 32);
        }
        LGKM_BARRIER();
    }

#pragma unroll
    for (int nt = 0; nt < 4; ++nt) {
        const int f = f0 + wn + nt * 16 + c;
        const float bj = Bias[f];
#pragma unroll
        for (int mt = 0; mt < 4; ++mt) {
#pragma unroll
            for (int r = 0; r < 4; ++r) {
                const int n = n0 + wm + mt * 16 + quad * 4 + r;
                Out[(size_t)n * E_DIM + f] = acc[mt][nt][r] + bj;
            }
        }
    }
}

// ---------------------------------------------------------------------------
extern "C" void kernel_launch(void* const* d_in, const int* in_sizes, int n_in,
                              void* d_out, int out_size, void* d_ws, size_t ws_size,
                              hipStream_t stream) {
    const float* q_in = (const float*)d_in[0];
    const float* k_in = (const float*)d_in[1];
    const float* v_in = (const float*)d_in[2];
    const float* ipw  = (const float*)d_in[3];
    const float* ipb  = (const float*)d_in[4];
    const float* opw  = (const float*)d_in[5];
    const float* opb  = (const float*)d_in[6];
    const float* tab  = (const float*)d_in[7];
    const int*   rpe  = (const int*)d_in[8];
    float* out = (float*)d_out;

    f16* ws   = (f16*)d_ws;
    f16* Q    = ws;
    f16* K    = ws + 8388608;
    f16* Vt   = ws + 16777216;
    f16* CTX  = ws + 25165824;

    qkv_kernel<<<dim3(1536), 256, 0, stream>>>(q_in, k_in, v_in, ipw, ipb, Q, K, Vt);
    attn_kernel<<<dim3(1024), 256, 0, stream>>>(Q, K, Vt, rpe, tab, CTX);
    out_kernel<<<dim3(512), 256, 0, stream>>>(CTX, opw, opb, out);
}